// Round 11
// baseline (195.268 us; speedup 1.0000x reference)
//
#include <hip/hip_runtime.h>
#include <hip/hip_bf16.h>
#include <math.h>

#define NW 4096
#define NL 32
#define ND 256
#define ND2 512

typedef __attribute__((ext_vector_type(8))) short short8;
typedef __attribute__((ext_vector_type(4))) float floatx4;

__device__ inline float bitsf(unsigned u) {
  union { unsigned u; float f; } v;
  v.u = u;
  return v.f;
}

// ---------------------------------------------------------------------------
// ws layout:
//   wT    fp32 [3][256][256]
//   part  fp32 [512][64]
//   h     fp32 [1024]
//   ctr   int[8]   ctr[0]=sent arrivals(512), ctr[4]=fc1 arrivals(8)
//   Tb    bf16 [4 cotile][3 k][128 c][64 co]
//   u     bf16 [4098][512]  (guard rows at both ends)
//   Wb    bf16 [3][512 co][512 ci]
//
// R10 accounting: bodies ~32us, fills ~84us, ~10us PER KERNEL launch tax.
// R11: fc12 merged into sent (5->4 kernels) via cheap-release chain —
// sent blocks release with only 256B dirty (fc12-regime, proven free),
// 8 trailing fc blocks spin+acquire once. R6's storm was releases under
// concurrent MB-scale dirtying; sent's tail is not that regime.
// ---------------------------------------------------------------------------

// K1: prep (R7 body + 8-int ctr zero). 3841 blocks.
__global__ __launch_bounds__(256) void prep_kernel(
    const float* __restrict__ conv_sent_w, const float* __restrict__ conv_chr_w,
    float* __restrict__ wT, __hip_bfloat16* __restrict__ Wb,
    short* __restrict__ u_base, int* __restrict__ ctr) {
  int b = blockIdx.x;
  int tid = threadIdx.x;
  if (b < 3072) {                         // Wb: output-indexed coalesced
    int idx = b * 256 + tid;              // idx = k*262144 + co*512 + ci
    int k = idx >> 18;
    int rem = idx & 262143;
    int co = rem >> 9;
    int ci = rem & 511;
    Wb[idx] = __float2bfloat16(conv_sent_w[co * 1536 + ci * 3 + k]);
  } else if (b < 3840) {                  // chr w -> wT
    int idx = (b - 3072) * 256 + tid;
    float v = conv_chr_w[idx];
    int co = idx / 768;
    int rem = idx - co * 768;
    int ci = rem / 3;
    int k = rem - ci * 3;
    wT[k * 65536 + ci * 256 + co] = v;
  } else {                                // guard rows + ctr
    u_base[tid] = 0;
    u_base[tid + 256] = 0;
    u_base[4097 * 512 + tid] = 0;
    u_base[4097 * 512 + tid + 256] = 0;
    if (tid < 8) ctr[tid] = 0;
  }
}

// K2: table (R7-verbatim). grid 96.
__global__ __launch_bounds__(256) void table_kernel(
    const float* __restrict__ chr_emb, const float* __restrict__ wT,
    __hip_bfloat16* __restrict__ Tb) {
  __shared__ float s_e[4][256];
  int k = blockIdx.x >> 5;
  int c0 = (blockIdx.x & 31) * 4;
  int co = threadIdx.x;
#pragma unroll
  for (int j = 0; j < 4; ++j) s_e[j][co] = chr_emb[(c0 + j) * 256 + co];
  __syncthreads();
  const float* wk = wT + k * 65536;
  float a0 = 0.f, a1 = 0.f, a2 = 0.f, a3 = 0.f;
#pragma unroll 8
  for (int ci = 0; ci < 256; ++ci) {
    float w = wk[ci * 256 + co];
    a0 = fmaf(s_e[0][ci], w, a0);
    a1 = fmaf(s_e[1][ci], w, a1);
    a2 = fmaf(s_e[2][ci], w, a2);
    a3 = fmaf(s_e[3][ci], w, a3);
  }
  int base = ((co >> 6) * 3 + k) * 8192 + (co & 63);
  Tb[base + (c0 + 0) * 64] = __float2bfloat16(a0);
  Tb[base + (c0 + 1) * 64] = __float2bfloat16(a1);
  Tb[base + (c0 + 2) * 64] = __float2bfloat16(a2);
  Tb[base + (c0 + 3) * 64] = __float2bfloat16(a3);
}

// K3: char conv + word-emb gather (R7-verbatim). 512 blocks.
__global__ __launch_bounds__(256) void char_word_kernel(
    const int* __restrict__ words, const int* __restrict__ wic,
    const __hip_bfloat16* __restrict__ Tb, const float* __restrict__ word_emb,
    const float* __restrict__ bias, __hip_bfloat16* __restrict__ u0) {
  __shared__ short sT[3 * 128 * 64];   // 48 KB
  __shared__ int s_wic[32 * 32];       // 4 KB
  __shared__ int s_wid[32];
  const int ct = blockIdx.x >> 7;
  const int w0 = (blockIdx.x & 127) * 32;
  const int tid = threadIdx.x;
  {
    const uint4* src = (const uint4*)((const short*)Tb + ct * 24576);
    uint4* dst = (uint4*)sT;
#pragma unroll
    for (int i = 0; i < 12; ++i) dst[tid + i * 256] = src[tid + i * 256];
    ((int4*)s_wic)[tid] = ((const int4*)(wic + w0 * 32))[tid];
    if (tid < 32) s_wid[tid] = words[w0 + tid];
  }
  __syncthreads();
  {
    const int co_l = tid & 63, slot = tid >> 6;
#pragma unroll
    for (int wi = 0; wi < 8; ++wi) {
      int wl = slot * 8 + wi;
      u0[(w0 + wl) * ND2 + ct * 64 + co_l] =
          __float2bfloat16(word_emb[s_wid[wl] * ND + ct * 64 + co_l]);
    }
  }
  const int wave = tid >> 6, lane = tid & 63;
  const int half = lane >> 5, co2 = (lane & 31) * 2;
  const float2 bb = *(const float2*)&bias[ct * 64 + co2];
  const short* T0p = sT;
  const short* T1p = sT + 8192;
  const short* T2p = sT + 16384;
#pragma unroll
  for (int p = 0; p < 4; ++p) {
    const int wl = wave * 8 + p * 2 + half;
    int chv[32];
    const int4* c4 = (const int4*)(s_wic + wl * 32);
#pragma unroll
    for (int j = 0; j < 8; ++j) {
      int4 cc = c4[j];
      chv[4 * j + 0] = cc.x; chv[4 * j + 1] = cc.y;
      chv[4 * j + 2] = cc.z; chv[4 * j + 3] = cc.w;
    }
    float m0 = -INFINITY, m1 = -INFINITY;
#pragma unroll
    for (int t = 0; t < NL; ++t) {
      unsigned v1 = *(const unsigned*)&T1p[chv[t] * 64 + co2];
      float s0 = bitsf(v1 << 16);
      float s1 = bitsf(v1 & 0xffff0000u);
      if (t > 0) {
        unsigned v0 = *(const unsigned*)&T0p[chv[t - 1] * 64 + co2];
        s0 += bitsf(v0 << 16);
        s1 += bitsf(v0 & 0xffff0000u);
      }
      if (t < NL - 1) {
        unsigned v2 = *(const unsigned*)&T2p[chv[t + 1] * 64 + co2];
        s0 += bitsf(v2 << 16);
        s1 += bitsf(v2 & 0xffff0000u);
      }
      m0 = fmaxf(m0, s0);
      m1 = fmaxf(m1, s1);
    }
    __hip_bfloat162 hh;
    hh.x = __float2bfloat16(m0 + bb.x);
    hh.y = __float2bfloat16(m1 + bb.y);
    *(__hip_bfloat162*)&u0[(w0 + wl) * ND2 + ND + ct * 64 + co2] = hh;
  }
}

// K4: sent conv GEMM + fc1 + fc2, merged. grid (65, 8) x 256 threads.
//   x < 64:  R7-verbatim sent tile -> part -> cheap release arrive (ctr[0])
//   x == 64: fc block (8 total): spin ctr[0]==512, acquire, fc1 (128 outputs),
//            release ctr[4]; last of 8 runs fc2 (R7-verbatim arithmetic).
__global__ __launch_bounds__(256, 2) void sent_fc_kernel(
    const __hip_bfloat16* __restrict__ u0,
    const __hip_bfloat16* __restrict__ Wb,
    float* __restrict__ partial, const float* __restrict__ bs,
    const float* __restrict__ w1, const float* __restrict__ b1,
    const float* __restrict__ w2, const float* __restrict__ b2,
    float* __restrict__ h, int* __restrict__ ctr, float* __restrict__ out) {
  __shared__ short As[2][64 * 64];   // 16 KB
  __shared__ short Bs[2][64 * 64];   // 16 KB
  __shared__ float sm[4][32];
  __shared__ float s_r[512];
  __shared__ int s_last;
  const int tid = threadIdx.x;
  const int bx = blockIdx.x;

  if (bx == 64) {
    // ---------------- fc block ----------------
    if (tid == 0) {
      while (__hip_atomic_load(ctr, __ATOMIC_RELAXED, __HIP_MEMORY_SCOPE_AGENT) < 512)
        __builtin_amdgcn_s_sleep(8);
    }
    __syncthreads();
    __builtin_amdgcn_fence(__ATOMIC_ACQUIRE, "agent");
    // s_r: same per-row op order as R7 fc12 -> bit-exact
#pragma unroll
    for (int rep = 0; rep < 2; ++rep) {
      int row = tid + rep * 256;
      const float4* p = (const float4*)(partial + row * 64);
      float mm = -INFINITY;
#pragma unroll
      for (int j = 0; j < 16; ++j) {
        float4 v = p[j];
        mm = fmaxf(mm, fmaxf(fmaxf(v.x, v.y), fmaxf(v.z, v.w)));
      }
      s_r[row] = mm + bs[row];
    }
    __syncthreads();
    const int wave = tid >> 6, lane = tid & 63;
    const float4* rv = (const float4*)(s_r + lane * 8);
    float4 r0 = rv[0], r1 = rv[1];
#pragma unroll 4
    for (int i = 0; i < 32; ++i) {
      int o = blockIdx.y * 128 + wave * 32 + i;
      const float4* wv = (const float4*)(w1 + o * 512 + lane * 8);
      float4 w0 = wv[0], w1v = wv[1];
      float acc = w0.x * r0.x + w0.y * r0.y + w0.z * r0.z + w0.w * r0.w +
                  w1v.x * r1.x + w1v.y * r1.y + w1v.z * r1.z + w1v.w * r1.w;
#pragma unroll
      for (int off = 32; off >= 1; off >>= 1) acc += __shfl_down(acc, off, 64);
      if (lane == 0) h[o] = tanhf(acc + b1[o]);
    }
    __syncthreads();                 // drain h stores
    if (tid == 0) {
      int old = __hip_atomic_fetch_add(ctr + 4, 1, __ATOMIC_RELEASE,
                                       __HIP_MEMORY_SCOPE_AGENT);
      s_last = (old == 7) ? 1 : 0;
    }
    __syncthreads();
    if (s_last) {
      __builtin_amdgcn_fence(__ATOMIC_ACQUIRE, "agent");
      if (tid < 128) {
        int o2 = tid >> 6, lane2 = tid & 63;
        float acc2 = 0.f;
#pragma unroll
        for (int j = 0; j < 16; ++j)
          acc2 = fmaf(w2[o2 * 1024 + lane2 + j * 64], h[lane2 + j * 64], acc2);
#pragma unroll
        for (int off = 32; off >= 1; off >>= 1) acc2 += __shfl_down(acc2, off, 64);
        if (lane2 == 0) out[o2] = acc2 + b2[o2];
      }
    }
    return;
  }

  // ---------------- sent tile (R7-verbatim) ----------------
  const int t0 = bx * 64;
  const int co0 = blockIdx.y * 64;
  const int wave = tid >> 6, lane = tid & 63;
  const int wy = wave >> 1, wx = wave & 1;
  const int m = lane & 15, q = lane >> 4;

  floatx4 acc[2][2];
#pragma unroll
  for (int i = 0; i < 2; ++i)
#pragma unroll
    for (int j = 0; j < 2; ++j) acc[i][j] = (floatx4){0.f, 0.f, 0.f, 0.f};

  int aoff[2][2], boff[2][2];
#pragma unroll
  for (int kk = 0; kk < 2; ++kk) {
#pragma unroll
    for (int i = 0; i < 2; ++i) {
      int row = wy * 32 + i * 16 + m;
      aoff[kk][i] = row * 64 + (((kk * 4 + q) ^ (row & 7)) * 8);
      row = wx * 32 + i * 16 + m;
      boff[kk][i] = row * 64 + (((kk * 4 + q) ^ (row & 7)) * 8);
    }
  }

  const int sc = tid & 7, sr = tid >> 3;
  const int swc = (sc ^ (sr & 7)) * 8;
  const short* WbS = (const short*)Wb;
  const short* uS = (const short*)u0;

  uint4 ra0, ra1, rb0, rb1;
  auto LOADS = [&](int s2) {
    int k = s2 >> 3, ci0 = (s2 & 7) << 6;
    const short* WbK = WbS + k * 262144 + (co0 + sr) * 512 + ci0 + sc * 8;
    const short* uK = uS + (t0 + sr + k - 1) * 512 + ci0 + sc * 8;
    ra0 = *(const uint4*)(WbK);
    ra1 = *(const uint4*)(WbK + 32 * 512);
    rb0 = *(const uint4*)(uK);
    rb1 = *(const uint4*)(uK + 32 * 512);
  };
  auto WRITE = [&](int buf) {
    *(uint4*)&As[buf][sr * 64 + swc] = ra0;
    *(uint4*)&As[buf][(sr + 32) * 64 + swc] = ra1;
    *(uint4*)&Bs[buf][sr * 64 + swc] = rb0;
    *(uint4*)&Bs[buf][(sr + 32) * 64 + swc] = rb1;
  };
  auto MFMA = [&](int buf) {
#pragma unroll
    for (int kk = 0; kk < 2; ++kk) {
      short8 av0 = *(const short8*)&As[buf][aoff[kk][0]];
      short8 av1 = *(const short8*)&As[buf][aoff[kk][1]];
      short8 bv0 = *(const short8*)&Bs[buf][boff[kk][0]];
      short8 bv1 = *(const short8*)&Bs[buf][boff[kk][1]];
      acc[0][0] = __builtin_amdgcn_mfma_f32_16x16x32_bf16(av0, bv0, acc[0][0], 0, 0, 0);
      acc[0][1] = __builtin_amdgcn_mfma_f32_16x16x32_bf16(av0, bv1, acc[0][1], 0, 0, 0);
      acc[1][0] = __builtin_amdgcn_mfma_f32_16x16x32_bf16(av1, bv0, acc[1][0], 0, 0, 0);
      acc[1][1] = __builtin_amdgcn_mfma_f32_16x16x32_bf16(av1, bv1, acc[1][1], 0, 0, 0);
    }
  };

  LOADS(0);
  WRITE(0);
  __syncthreads();
  for (int s = 0; s < 23; ++s) {
    LOADS(s + 1);
    MFMA(s & 1);
    WRITE((s + 1) & 1);
    __syncthreads();
  }
  MFMA(23 & 1);

#pragma unroll
  for (int i = 0; i < 2; ++i)
#pragma unroll
    for (int r = 0; r < 4; ++r) {
      float x = fmaxf(acc[i][0][r], acc[i][1][r]);
#pragma unroll
      for (int off = 1; off < 16; off <<= 1)
        x = fmaxf(x, __shfl_xor(x, off, 64));
      if (m == 0) sm[wave][i * 16 + q * 4 + r] = x;
    }
  __syncthreads();
  if (tid < 64) {
    int whalf = tid >> 5;
    float v = fmaxf(sm[whalf * 2 + 0][tid & 31], sm[whalf * 2 + 1][tid & 31]);
    partial[(co0 + tid) * 64 + bx] = v;
  }
  // cheap-release arrive: only this block's 256B part slice is dirty
  __syncthreads();                   // drains the part stores (vmcnt before barrier)
  if (tid == 0)
    __hip_atomic_fetch_add(ctr, 1, __ATOMIC_RELEASE, __HIP_MEMORY_SCOPE_AGENT);
}

extern "C" void kernel_launch(void* const* d_in, const int* in_sizes, int n_in,
                              void* d_out, int out_size, void* d_ws, size_t ws_size,
                              hipStream_t stream) {
  const int*   words       = (const int*)d_in[0];
  const int*   wic         = (const int*)d_in[1];
  const float* word_emb    = (const float*)d_in[2];
  const float* chr_emb     = (const float*)d_in[3];
  const float* conv_chr_w  = (const float*)d_in[4];
  const float* conv_chr_b  = (const float*)d_in[5];
  const float* conv_sent_w = (const float*)d_in[6];
  const float* conv_sent_b = (const float*)d_in[7];
  const float* w1          = (const float*)d_in[8];
  const float* b1          = (const float*)d_in[9];
  const float* w2          = (const float*)d_in[10];
  const float* b2          = (const float*)d_in[11];
  float* out = (float*)d_out;

  float* ws    = (float*)d_ws;
  float* wT    = ws;                        // 196608 f
  float* part  = wT + 196608;               // 32768 f
  float* h_buf = part + 32768;              // 1024 f
  int*   ctr   = (int*)(h_buf + 1024);      // 8 ints
  short* Tb    = (short*)(ctr + 8);         // 98304 bf16
  short* u_base = Tb + 98304;               // 4098*512 bf16
  __hip_bfloat16* u0 = (__hip_bfloat16*)(u_base + 512);
  __hip_bfloat16* Wb = (__hip_bfloat16*)(u_base + 4098 * 512);

  prep_kernel<<<3841, 256, 0, stream>>>(conv_sent_w, conv_chr_w, wT, Wb,
                                        u_base, ctr);
  table_kernel<<<96, 256, 0, stream>>>(chr_emb, wT, (__hip_bfloat16*)Tb);
  char_word_kernel<<<512, 256, 0, stream>>>(words, wic, (const __hip_bfloat16*)Tb,
                                            word_emb, conv_chr_b, u0);
  sent_fc_kernel<<<dim3(65, 8), 256, 0, stream>>>(u0, Wb, part, conv_sent_b,
                                                  w1, b1, w2, b2, h_buf, ctr, out);
}

// Round 12
// 158.010 us; speedup vs baseline: 1.2358x; 1.2358x over previous
//
#include <hip/hip_runtime.h>
#include <hip/hip_bf16.h>
#include <math.h>

#define NW 4096
#define NL 32
#define ND 256
#define ND2 512

typedef __attribute__((ext_vector_type(8))) short short8;
typedef __attribute__((ext_vector_type(4))) float floatx4;

__device__ inline float bitsf(unsigned u) {
  union { unsigned u; float f; } v;
  v.u = u;
  return v.f;
}

// ---------------------------------------------------------------------------
// ws layout: identical to R7.
//
// R11 lesson (final): mid-kernel agent-scope releases flush L2 under
// concurrent readers -> 6-7x refetch storm. Producer->consumer fusion via
// release chains abandoned (0-for-3). R12: back to R7's 5-kernel chain;
// sent re-tiled 32co x 64t (1024 blocks, 24.5KB LDS -> 4 blocks/CU,
// 16 waves/CU, 2x latency hiding). Same per-fragment MFMA order -> bit-exact.
// ---------------------------------------------------------------------------

// K1: prep (R7-verbatim). 3841 blocks.
__global__ __launch_bounds__(256) void prep_kernel(
    const float* __restrict__ conv_sent_w, const float* __restrict__ conv_chr_w,
    float* __restrict__ wT, __hip_bfloat16* __restrict__ Wb,
    short* __restrict__ u_base, int* __restrict__ ctr) {
  int b = blockIdx.x;
  int tid = threadIdx.x;
  if (b < 3072) {                         // Wb: output-indexed coalesced
    int idx = b * 256 + tid;              // idx = k*262144 + co*512 + ci
    int k = idx >> 18;
    int rem = idx & 262143;
    int co = rem >> 9;
    int ci = rem & 511;
    Wb[idx] = __float2bfloat16(conv_sent_w[co * 1536 + ci * 3 + k]);
  } else if (b < 3840) {                  // chr w -> wT
    int idx = (b - 3072) * 256 + tid;
    float v = conv_chr_w[idx];
    int co = idx / 768;
    int rem = idx - co * 768;
    int ci = rem / 3;
    int k = rem - ci * 3;
    wT[k * 65536 + ci * 256 + co] = v;
  } else {                                // guard rows + ctr
    u_base[tid] = 0;
    u_base[tid + 256] = 0;
    u_base[4097 * 512 + tid] = 0;
    u_base[4097 * 512 + tid + 256] = 0;
    if (tid == 0) ctr[0] = 0;
  }
}

// K2: table (R7-verbatim). grid 96.
__global__ __launch_bounds__(256) void table_kernel(
    const float* __restrict__ chr_emb, const float* __restrict__ wT,
    __hip_bfloat16* __restrict__ Tb) {
  __shared__ float s_e[4][256];
  int k = blockIdx.x >> 5;
  int c0 = (blockIdx.x & 31) * 4;
  int co = threadIdx.x;
#pragma unroll
  for (int j = 0; j < 4; ++j) s_e[j][co] = chr_emb[(c0 + j) * 256 + co];
  __syncthreads();
  const float* wk = wT + k * 65536;
  float a0 = 0.f, a1 = 0.f, a2 = 0.f, a3 = 0.f;
#pragma unroll 8
  for (int ci = 0; ci < 256; ++ci) {
    float w = wk[ci * 256 + co];
    a0 = fmaf(s_e[0][ci], w, a0);
    a1 = fmaf(s_e[1][ci], w, a1);
    a2 = fmaf(s_e[2][ci], w, a2);
    a3 = fmaf(s_e[3][ci], w, a3);
  }
  int base = ((co >> 6) * 3 + k) * 8192 + (co & 63);
  Tb[base + (c0 + 0) * 64] = __float2bfloat16(a0);
  Tb[base + (c0 + 1) * 64] = __float2bfloat16(a1);
  Tb[base + (c0 + 2) * 64] = __float2bfloat16(a2);
  Tb[base + (c0 + 3) * 64] = __float2bfloat16(a3);
}

// K3: char conv + word-emb gather (R7-verbatim). 512 blocks.
__global__ __launch_bounds__(256) void char_word_kernel(
    const int* __restrict__ words, const int* __restrict__ wic,
    const __hip_bfloat16* __restrict__ Tb, const float* __restrict__ word_emb,
    const float* __restrict__ bias, __hip_bfloat16* __restrict__ u0) {
  __shared__ short sT[3 * 128 * 64];   // 48 KB
  __shared__ int s_wic[32 * 32];       // 4 KB
  __shared__ int s_wid[32];
  const int ct = blockIdx.x >> 7;
  const int w0 = (blockIdx.x & 127) * 32;
  const int tid = threadIdx.x;
  {
    const uint4* src = (const uint4*)((const short*)Tb + ct * 24576);
    uint4* dst = (uint4*)sT;
#pragma unroll
    for (int i = 0; i < 12; ++i) dst[tid + i * 256] = src[tid + i * 256];
    ((int4*)s_wic)[tid] = ((const int4*)(wic + w0 * 32))[tid];
    if (tid < 32) s_wid[tid] = words[w0 + tid];
  }
  __syncthreads();
  {
    const int co_l = tid & 63, slot = tid >> 6;
#pragma unroll
    for (int wi = 0; wi < 8; ++wi) {
      int wl = slot * 8 + wi;
      u0[(w0 + wl) * ND2 + ct * 64 + co_l] =
          __float2bfloat16(word_emb[s_wid[wl] * ND + ct * 64 + co_l]);
    }
  }
  const int wave = tid >> 6, lane = tid & 63;
  const int half = lane >> 5, co2 = (lane & 31) * 2;
  const float2 bb = *(const float2*)&bias[ct * 64 + co2];
  const short* T0p = sT;
  const short* T1p = sT + 8192;
  const short* T2p = sT + 16384;
#pragma unroll
  for (int p = 0; p < 4; ++p) {
    const int wl = wave * 8 + p * 2 + half;
    int chv[32];
    const int4* c4 = (const int4*)(s_wic + wl * 32);
#pragma unroll
    for (int j = 0; j < 8; ++j) {
      int4 cc = c4[j];
      chv[4 * j + 0] = cc.x; chv[4 * j + 1] = cc.y;
      chv[4 * j + 2] = cc.z; chv[4 * j + 3] = cc.w;
    }
    float m0 = -INFINITY, m1 = -INFINITY;
#pragma unroll
    for (int t = 0; t < NL; ++t) {
      unsigned v1 = *(const unsigned*)&T1p[chv[t] * 64 + co2];
      float s0 = bitsf(v1 << 16);
      float s1 = bitsf(v1 & 0xffff0000u);
      if (t > 0) {
        unsigned v0 = *(const unsigned*)&T0p[chv[t - 1] * 64 + co2];
        s0 += bitsf(v0 << 16);
        s1 += bitsf(v0 & 0xffff0000u);
      }
      if (t < NL - 1) {
        unsigned v2 = *(const unsigned*)&T2p[chv[t + 1] * 64 + co2];
        s0 += bitsf(v2 << 16);
        s1 += bitsf(v2 & 0xffff0000u);
      }
      m0 = fmaxf(m0, s0);
      m1 = fmaxf(m1, s1);
    }
    __hip_bfloat162 hh;
    hh.x = __float2bfloat16(m0 + bb.x);
    hh.y = __float2bfloat16(m1 + bb.y);
    *(__hip_bfloat162*)&u0[(w0 + wl) * ND2 + ND + ct * 64 + co2] = hh;
  }
}

// K4: sentence conv GEMM, re-tiled 32co x 64t. grid (64, 16) = 1024 blocks,
// 24.5KB LDS -> 4 blocks/CU (16 waves/CU). Wave w: wy=w>>1 co-half (16 co),
// wx=w&1 t-half (32 t); acc[2] over t 16-frags. Same per-fragment MFMA
// sequence (s asc, kk asc) and fmax pairing as R7 -> bit-exact.
__global__ __launch_bounds__(256, 4) void sent_conv_mfma(
    const __hip_bfloat16* __restrict__ u0,
    const __hip_bfloat16* __restrict__ Wb,
    float* __restrict__ partial) {
  __shared__ short As[2][32 * 64];   // 8 KB
  __shared__ short Bs[2][64 * 64];   // 16 KB
  __shared__ float sm[4][16];
  const int tid = threadIdx.x;
  const int t0 = blockIdx.x * 64;
  const int co0 = blockIdx.y * 32;
  const int wave = tid >> 6, lane = tid & 63;
  const int wy = wave >> 1, wx = wave & 1;
  const int m = lane & 15, q = lane >> 4;

  floatx4 acc[2];
  acc[0] = (floatx4){0.f, 0.f, 0.f, 0.f};
  acc[1] = (floatx4){0.f, 0.f, 0.f, 0.f};

  int aoff[2], boff[2][2];
#pragma unroll
  for (int kk = 0; kk < 2; ++kk) {
    int row = wy * 16 + m;
    aoff[kk] = row * 64 + (((kk * 4 + q) ^ (row & 7)) * 8);
#pragma unroll
    for (int j = 0; j < 2; ++j) {
      row = wx * 32 + j * 16 + m;
      boff[kk][j] = row * 64 + (((kk * 4 + q) ^ (row & 7)) * 8);
    }
  }

  const int sc = tid & 7, sr = tid >> 3;   // sr 0..31
  const int swc = (sc ^ (sr & 7)) * 8;
  const short* WbS = (const short*)Wb;
  const short* uS = (const short*)u0;

  uint4 ra0, rb0, rb1;
  auto LOADS = [&](int s2) {
    int k = s2 >> 3, ci0 = (s2 & 7) << 6;
    const short* WbK = WbS + k * 262144 + (co0 + sr) * 512 + ci0 + sc * 8;
    const short* uK = uS + (t0 + sr + k - 1) * 512 + ci0 + sc * 8;
    ra0 = *(const uint4*)(WbK);
    rb0 = *(const uint4*)(uK);
    rb1 = *(const uint4*)(uK + 32 * 512);
  };
  auto WRITE = [&](int buf) {
    *(uint4*)&As[buf][sr * 64 + swc] = ra0;
    *(uint4*)&Bs[buf][sr * 64 + swc] = rb0;
    *(uint4*)&Bs[buf][(sr + 32) * 64 + swc] = rb1;
  };
  auto MFMA = [&](int buf) {
#pragma unroll
    for (int kk = 0; kk < 2; ++kk) {
      short8 av = *(const short8*)&As[buf][aoff[kk]];
      short8 bv0 = *(const short8*)&Bs[buf][boff[kk][0]];
      short8 bv1 = *(const short8*)&Bs[buf][boff[kk][1]];
      acc[0] = __builtin_amdgcn_mfma_f32_16x16x32_bf16(av, bv0, acc[0], 0, 0, 0);
      acc[1] = __builtin_amdgcn_mfma_f32_16x16x32_bf16(av, bv1, acc[1], 0, 0, 0);
    }
  };

  LOADS(0);
  WRITE(0);
  __syncthreads();
  for (int s = 0; s < 23; ++s) {
    LOADS(s + 1);              // prefetch next step (latency under MFMAs)
    MFMA(s & 1);
    WRITE((s + 1) & 1);
    __syncthreads();           // ONE barrier per step
  }
  MFMA(23 & 1);

  // epilogue: max over t within block. co = co0 + wy*16 + q*4 + r.
#pragma unroll
  for (int r = 0; r < 4; ++r) {
    float x = fmaxf(acc[0][r], acc[1][r]);
#pragma unroll
    for (int off = 1; off < 16; off <<= 1)
      x = fmaxf(x, __shfl_xor(x, off, 64));
    if (m == 0) sm[wave][q * 4 + r] = x;
  }
  __syncthreads();
  if (tid < 32) {
    int wyh = tid >> 4;
    float v = fmaxf(sm[wyh * 2 + 0][tid & 15], sm[wyh * 2 + 1][tid & 15]);
    partial[(co0 + tid) * 64 + blockIdx.x] = v;
  }
}

// K5: fc1 + fc2 fused (R7-verbatim). grid 128 x 512 threads.
__global__ __launch_bounds__(512) void fc12_kernel(
    const float* __restrict__ partial, const float* __restrict__ bs,
    const float* __restrict__ w1, const float* __restrict__ b1,
    const float* __restrict__ w2, const float* __restrict__ b2,
    float* __restrict__ h, int* __restrict__ ctr, float* __restrict__ out) {
  __shared__ float s_r[512];
  __shared__ int s_last;
  int tid = threadIdx.x;
  {
    const float4* p = (const float4*)(partial + tid * 64);
    float mm = -INFINITY;
#pragma unroll
    for (int j = 0; j < 16; ++j) {
      float4 v = p[j];
      mm = fmaxf(mm, fmaxf(fmaxf(v.x, v.y), fmaxf(v.z, v.w)));
    }
    s_r[tid] = mm + bs[tid];
  }
  __syncthreads();
  int wave = tid >> 6, lane = tid & 63;
  int o = blockIdx.x * 8 + wave;
  const float4* wv = (const float4*)(w1 + o * 512 + lane * 8);
  const float4* rv = (const float4*)(s_r + lane * 8);
  float4 w0 = wv[0], w1v = wv[1];
  float4 r0 = rv[0], r1 = rv[1];
  float acc = w0.x * r0.x + w0.y * r0.y + w0.z * r0.z + w0.w * r0.w +
              w1v.x * r1.x + w1v.y * r1.y + w1v.z * r1.z + w1v.w * r1.w;
#pragma unroll
  for (int off = 32; off >= 1; off >>= 1) acc += __shfl_down(acc, off, 64);
  if (lane == 0) h[o] = tanhf(acc + b1[o]);
  __syncthreads();
  if (tid == 0) {
    int old = __hip_atomic_fetch_add(ctr, 1, __ATOMIC_RELEASE,
                                     __HIP_MEMORY_SCOPE_AGENT);
    s_last = (old == 127) ? 1 : 0;
  }
  __syncthreads();
  if (s_last) {
    __builtin_amdgcn_fence(__ATOMIC_ACQUIRE, "agent");
    if (tid < 128) {
      int o2 = tid >> 6;
      int lane2 = tid & 63;
      float acc2 = 0.f;
#pragma unroll
      for (int j = 0; j < 16; ++j)
        acc2 = fmaf(w2[o2 * 1024 + lane2 + j * 64], h[lane2 + j * 64], acc2);
#pragma unroll
      for (int off = 32; off >= 1; off >>= 1) acc2 += __shfl_down(acc2, off, 64);
      if (lane2 == 0) out[o2] = acc2 + b2[o2];
    }
  }
}

extern "C" void kernel_launch(void* const* d_in, const int* in_sizes, int n_in,
                              void* d_out, int out_size, void* d_ws, size_t ws_size,
                              hipStream_t stream) {
  const int*   words       = (const int*)d_in[0];
  const int*   wic         = (const int*)d_in[1];
  const float* word_emb    = (const float*)d_in[2];
  const float* chr_emb     = (const float*)d_in[3];
  const float* conv_chr_w  = (const float*)d_in[4];
  const float* conv_chr_b  = (const float*)d_in[5];
  const float* conv_sent_w = (const float*)d_in[6];
  const float* conv_sent_b = (const float*)d_in[7];
  const float* w1          = (const float*)d_in[8];
  const float* b1          = (const float*)d_in[9];
  const float* w2          = (const float*)d_in[10];
  const float* b2          = (const float*)d_in[11];
  float* out = (float*)d_out;

  float* ws    = (float*)d_ws;
  float* wT    = ws;                        // 196608 f
  float* part  = wT + 196608;               // 32768 f
  float* h_buf = part + 32768;              // 1024 f
  int*   ctr   = (int*)(h_buf + 1024);      // 4 ints
  short* Tb    = (short*)(ctr + 4);         // 98304 bf16
  short* u_base = Tb + 98304;               // 4098*512 bf16
  __hip_bfloat16* u0 = (__hip_bfloat16*)(u_base + 512);
  __hip_bfloat16* Wb = (__hip_bfloat16*)(u_base + 4098 * 512);

  prep_kernel<<<3841, 256, 0, stream>>>(conv_sent_w, conv_chr_w, wT, Wb,
                                        u_base, ctr);
  table_kernel<<<96, 256, 0, stream>>>(chr_emb, wT, (__hip_bfloat16*)Tb);
  char_word_kernel<<<512, 256, 0, stream>>>(words, wic, (const __hip_bfloat16*)Tb,
                                            word_emb, conv_chr_b, u0);
  sent_conv_mfma<<<dim3(64, 16), 256, 0, stream>>>(u0, Wb, part);
  fc12_kernel<<<128, 512, 0, stream>>>(part, conv_sent_b, w1, b1, w2, b2,
                                       h_buf, ctr, out);
}

// Round 13
// 156.009 us; speedup vs baseline: 1.2516x; 1.0128x over previous
//
#include <hip/hip_runtime.h>
#include <hip/hip_bf16.h>
#include <math.h>

#define NW 4096
#define NL 32
#define ND 256
#define ND2 512

typedef __attribute__((ext_vector_type(8))) short short8;
typedef __attribute__((ext_vector_type(4))) float floatx4;

__device__ inline float bitsf(unsigned u) {
  union { unsigned u; float f; } v;
  v.u = u;
  return v.f;
}

// ---------------------------------------------------------------------------
// ws layout: identical to R7.
//
// R12 lesson: sent is not TLP-starved (4 blocks/CU == 2 blocks/CU perf).
// The limiter is the 40-cycle load->use window in the R7 step (WRITE consumes
// the prefetch in the same iteration). R13: 2-deep pipeline — triple-buffer
// LDS, two named register sets; LOADS(s+2) issued at iter s, consumed at
// iter s+1 -> full-iteration latency window. Same MFMA order -> bit-exact.
// ---------------------------------------------------------------------------

// K1: prep (R7-verbatim). 3841 blocks.
__global__ __launch_bounds__(256) void prep_kernel(
    const float* __restrict__ conv_sent_w, const float* __restrict__ conv_chr_w,
    float* __restrict__ wT, __hip_bfloat16* __restrict__ Wb,
    short* __restrict__ u_base, int* __restrict__ ctr) {
  int b = blockIdx.x;
  int tid = threadIdx.x;
  if (b < 3072) {                         // Wb: output-indexed coalesced
    int idx = b * 256 + tid;              // idx = k*262144 + co*512 + ci
    int k = idx >> 18;
    int rem = idx & 262143;
    int co = rem >> 9;
    int ci = rem & 511;
    Wb[idx] = __float2bfloat16(conv_sent_w[co * 1536 + ci * 3 + k]);
  } else if (b < 3840) {                  // chr w -> wT
    int idx = (b - 3072) * 256 + tid;
    float v = conv_chr_w[idx];
    int co = idx / 768;
    int rem = idx - co * 768;
    int ci = rem / 3;
    int k = rem - ci * 3;
    wT[k * 65536 + ci * 256 + co] = v;
  } else {                                // guard rows + ctr
    u_base[tid] = 0;
    u_base[tid + 256] = 0;
    u_base[4097 * 512 + tid] = 0;
    u_base[4097 * 512 + tid + 256] = 0;
    if (tid == 0) ctr[0] = 0;
  }
}

// K2: table (R7-verbatim). grid 96.
__global__ __launch_bounds__(256) void table_kernel(
    const float* __restrict__ chr_emb, const float* __restrict__ wT,
    __hip_bfloat16* __restrict__ Tb) {
  __shared__ float s_e[4][256];
  int k = blockIdx.x >> 5;
  int c0 = (blockIdx.x & 31) * 4;
  int co = threadIdx.x;
#pragma unroll
  for (int j = 0; j < 4; ++j) s_e[j][co] = chr_emb[(c0 + j) * 256 + co];
  __syncthreads();
  const float* wk = wT + k * 65536;
  float a0 = 0.f, a1 = 0.f, a2 = 0.f, a3 = 0.f;
#pragma unroll 8
  for (int ci = 0; ci < 256; ++ci) {
    float w = wk[ci * 256 + co];
    a0 = fmaf(s_e[0][ci], w, a0);
    a1 = fmaf(s_e[1][ci], w, a1);
    a2 = fmaf(s_e[2][ci], w, a2);
    a3 = fmaf(s_e[3][ci], w, a3);
  }
  int base = ((co >> 6) * 3 + k) * 8192 + (co & 63);
  Tb[base + (c0 + 0) * 64] = __float2bfloat16(a0);
  Tb[base + (c0 + 1) * 64] = __float2bfloat16(a1);
  Tb[base + (c0 + 2) * 64] = __float2bfloat16(a2);
  Tb[base + (c0 + 3) * 64] = __float2bfloat16(a3);
}

// K3: char conv + word-emb gather (R7-verbatim). 512 blocks.
__global__ __launch_bounds__(256) void char_word_kernel(
    const int* __restrict__ words, const int* __restrict__ wic,
    const __hip_bfloat16* __restrict__ Tb, const float* __restrict__ word_emb,
    const float* __restrict__ bias, __hip_bfloat16* __restrict__ u0) {
  __shared__ short sT[3 * 128 * 64];   // 48 KB
  __shared__ int s_wic[32 * 32];       // 4 KB
  __shared__ int s_wid[32];
  const int ct = blockIdx.x >> 7;
  const int w0 = (blockIdx.x & 127) * 32;
  const int tid = threadIdx.x;
  {
    const uint4* src = (const uint4*)((const short*)Tb + ct * 24576);
    uint4* dst = (uint4*)sT;
#pragma unroll
    for (int i = 0; i < 12; ++i) dst[tid + i * 256] = src[tid + i * 256];
    ((int4*)s_wic)[tid] = ((const int4*)(wic + w0 * 32))[tid];
    if (tid < 32) s_wid[tid] = words[w0 + tid];
  }
  __syncthreads();
  {
    const int co_l = tid & 63, slot = tid >> 6;
#pragma unroll
    for (int wi = 0; wi < 8; ++wi) {
      int wl = slot * 8 + wi;
      u0[(w0 + wl) * ND2 + ct * 64 + co_l] =
          __float2bfloat16(word_emb[s_wid[wl] * ND + ct * 64 + co_l]);
    }
  }
  const int wave = tid >> 6, lane = tid & 63;
  const int half = lane >> 5, co2 = (lane & 31) * 2;
  const float2 bb = *(const float2*)&bias[ct * 64 + co2];
  const short* T0p = sT;
  const short* T1p = sT + 8192;
  const short* T2p = sT + 16384;
#pragma unroll
  for (int p = 0; p < 4; ++p) {
    const int wl = wave * 8 + p * 2 + half;
    int chv[32];
    const int4* c4 = (const int4*)(s_wic + wl * 32);
#pragma unroll
    for (int j = 0; j < 8; ++j) {
      int4 cc = c4[j];
      chv[4 * j + 0] = cc.x; chv[4 * j + 1] = cc.y;
      chv[4 * j + 2] = cc.z; chv[4 * j + 3] = cc.w;
    }
    float m0 = -INFINITY, m1 = -INFINITY;
#pragma unroll
    for (int t = 0; t < NL; ++t) {
      unsigned v1 = *(const unsigned*)&T1p[chv[t] * 64 + co2];
      float s0 = bitsf(v1 << 16);
      float s1 = bitsf(v1 & 0xffff0000u);
      if (t > 0) {
        unsigned v0 = *(const unsigned*)&T0p[chv[t - 1] * 64 + co2];
        s0 += bitsf(v0 << 16);
        s1 += bitsf(v0 & 0xffff0000u);
      }
      if (t < NL - 1) {
        unsigned v2 = *(const unsigned*)&T2p[chv[t + 1] * 64 + co2];
        s0 += bitsf(v2 << 16);
        s1 += bitsf(v2 & 0xffff0000u);
      }
      m0 = fmaxf(m0, s0);
      m1 = fmaxf(m1, s1);
    }
    __hip_bfloat162 hh;
    hh.x = __float2bfloat16(m0 + bb.x);
    hh.y = __float2bfloat16(m1 + bb.y);
    *(__hip_bfloat162*)&u0[(w0 + wl) * ND2 + ND + ct * 64 + co2] = hh;
  }
}

// K4: sentence conv GEMM, 2-deep pipelined. grid (64, 8), 2 blocks/CU.
// Triple-buffer LDS; two named register sets (A: even steps, B: odd steps).
// iter s: LOADS(s+2) -> set(s%2); MFMA(buf s%3); WRITE set((s+1)%2) -> buf
// (s+1)%3; barrier. Load->consume distance = one full iteration.
#define SENT_LOADS(ra0, ra1, rb0, rb1, s2)                                   \
  {                                                                          \
    const int k_ = (s2) >> 3, ci0_ = ((s2) & 7) << 6;                        \
    const short* WbK = WbS + k_ * 262144 + (co0 + sr) * 512 + ci0_ + sc * 8; \
    const short* uK = uS + (t0 + sr + k_ - 1) * 512 + ci0_ + sc * 8;         \
    ra0 = *(const uint4*)(WbK);                                              \
    ra1 = *(const uint4*)(WbK + 32 * 512);                                   \
    rb0 = *(const uint4*)(uK);                                               \
    rb1 = *(const uint4*)(uK + 32 * 512);                                    \
  }
#define SENT_WRITE(ra0, ra1, rb0, rb1, buf)                                  \
  {                                                                          \
    *(uint4*)&As[buf][sr * 64 + swc] = ra0;                                  \
    *(uint4*)&As[buf][(sr + 32) * 64 + swc] = ra1;                           \
    *(uint4*)&Bs[buf][sr * 64 + swc] = rb0;                                  \
    *(uint4*)&Bs[buf][(sr + 32) * 64 + swc] = rb1;                           \
  }

__global__ __launch_bounds__(256, 2) void sent_conv_mfma(
    const __hip_bfloat16* __restrict__ u0,
    const __hip_bfloat16* __restrict__ Wb,
    float* __restrict__ partial) {
  __shared__ short As[3][64 * 64];   // 24 KB
  __shared__ short Bs[3][64 * 64];   // 24 KB
  __shared__ float sm[4][32];
  const int tid = threadIdx.x;
  const int t0 = blockIdx.x * 64;
  const int co0 = blockIdx.y * 64;
  const int wave = tid >> 6, lane = tid & 63;
  const int wy = wave >> 1, wx = wave & 1;
  const int m = lane & 15, q = lane >> 4;

  floatx4 acc[2][2];
#pragma unroll
  for (int i = 0; i < 2; ++i)
#pragma unroll
    for (int j = 0; j < 2; ++j) acc[i][j] = (floatx4){0.f, 0.f, 0.f, 0.f};

  int aoff[2][2], boff[2][2];
#pragma unroll
  for (int kk = 0; kk < 2; ++kk) {
#pragma unroll
    for (int i = 0; i < 2; ++i) {
      int row = wy * 32 + i * 16 + m;
      aoff[kk][i] = row * 64 + (((kk * 4 + q) ^ (row & 7)) * 8);
      row = wx * 32 + i * 16 + m;
      boff[kk][i] = row * 64 + (((kk * 4 + q) ^ (row & 7)) * 8);
    }
  }

  const int sc = tid & 7, sr = tid >> 3;
  const int swc = (sc ^ (sr & 7)) * 8;
  const short* WbS = (const short*)Wb;
  const short* uS = (const short*)u0;

  uint4 raA0, raA1, rbA0, rbA1;   // set A (even steps)
  uint4 raB0, raB1, rbB0, rbB1;   // set B (odd steps)

  auto MFMA = [&](int buf) {
#pragma unroll
    for (int kk = 0; kk < 2; ++kk) {
      short8 av0 = *(const short8*)&As[buf][aoff[kk][0]];
      short8 av1 = *(const short8*)&As[buf][aoff[kk][1]];
      short8 bv0 = *(const short8*)&Bs[buf][boff[kk][0]];
      short8 bv1 = *(const short8*)&Bs[buf][boff[kk][1]];
      acc[0][0] = __builtin_amdgcn_mfma_f32_16x16x32_bf16(av0, bv0, acc[0][0], 0, 0, 0);
      acc[0][1] = __builtin_amdgcn_mfma_f32_16x16x32_bf16(av0, bv1, acc[0][1], 0, 0, 0);
      acc[1][0] = __builtin_amdgcn_mfma_f32_16x16x32_bf16(av1, bv0, acc[1][0], 0, 0, 0);
      acc[1][1] = __builtin_amdgcn_mfma_f32_16x16x32_bf16(av1, bv1, acc[1][1], 0, 0, 0);
    }
  };

  // prologue: steps 0 (set A) and 1 (set B) in flight; buf0 written.
  SENT_LOADS(raA0, raA1, rbA0, rbA1, 0);
  SENT_LOADS(raB0, raB1, rbB0, rbB1, 1);
  SENT_WRITE(raA0, raA1, rbA0, rbA1, 0);
  __syncthreads();

#pragma unroll
  for (int s = 0; s < 24; ++s) {
    if (s + 2 < 24) {
      if ((s & 1) == 0) {
        SENT_LOADS(raA0, raA1, rbA0, rbA1, s + 2);   // set A free (written at s-1)
      } else {
        SENT_LOADS(raB0, raB1, rbB0, rbB1, s + 2);
      }
    }
    MFMA(s % 3);
    if (s + 1 < 24) {
      if ((s & 1) == 0) {
        SENT_WRITE(raB0, raB1, rbB0, rbB1, (s + 1) % 3);  // s+1 odd -> set B
      } else {
        SENT_WRITE(raA0, raA1, rbA0, rbA1, (s + 1) % 3);  // s+1 even -> set A
      }
      __syncthreads();
    }
  }

  // epilogue: max over t within block (R7-verbatim)
#pragma unroll
  for (int i = 0; i < 2; ++i)
#pragma unroll
    for (int r = 0; r < 4; ++r) {
      float x = fmaxf(acc[i][0][r], acc[i][1][r]);
#pragma unroll
      for (int off = 1; off < 16; off <<= 1)
        x = fmaxf(x, __shfl_xor(x, off, 64));
      if (m == 0) sm[wave][i * 16 + q * 4 + r] = x;
    }
  __syncthreads();
  if (tid < 64) {
    int whalf = tid >> 5;
    float v = fmaxf(sm[whalf * 2 + 0][tid & 31], sm[whalf * 2 + 1][tid & 31]);
    partial[(co0 + tid) * 64 + blockIdx.x] = v;
  }
}

// K5: fc1 + fc2 fused (R7-verbatim). grid 128 x 512 threads.
__global__ __launch_bounds__(512) void fc12_kernel(
    const float* __restrict__ partial, const float* __restrict__ bs,
    const float* __restrict__ w1, const float* __restrict__ b1,
    const float* __restrict__ w2, const float* __restrict__ b2,
    float* __restrict__ h, int* __restrict__ ctr, float* __restrict__ out) {
  __shared__ float s_r[512];
  __shared__ int s_last;
  int tid = threadIdx.x;
  {
    const float4* p = (const float4*)(partial + tid * 64);
    float mm = -INFINITY;
#pragma unroll
    for (int j = 0; j < 16; ++j) {
      float4 v = p[j];
      mm = fmaxf(mm, fmaxf(fmaxf(v.x, v.y), fmaxf(v.z, v.w)));
    }
    s_r[tid] = mm + bs[tid];
  }
  __syncthreads();
  int wave = tid >> 6, lane = tid & 63;
  int o = blockIdx.x * 8 + wave;
  const float4* wv = (const float4*)(w1 + o * 512 + lane * 8);
  const float4* rv = (const float4*)(s_r + lane * 8);
  float4 w0 = wv[0], w1v = wv[1];
  float4 r0 = rv[0], r1 = rv[1];
  float acc = w0.x * r0.x + w0.y * r0.y + w0.z * r0.z + w0.w * r0.w +
              w1v.x * r1.x + w1v.y * r1.y + w1v.z * r1.z + w1v.w * r1.w;
#pragma unroll
  for (int off = 32; off >= 1; off >>= 1) acc += __shfl_down(acc, off, 64);
  if (lane == 0) h[o] = tanhf(acc + b1[o]);
  __syncthreads();
  if (tid == 0) {
    int old = __hip_atomic_fetch_add(ctr, 1, __ATOMIC_RELEASE,
                                     __HIP_MEMORY_SCOPE_AGENT);
    s_last = (old == 127) ? 1 : 0;
  }
  __syncthreads();
  if (s_last) {
    __builtin_amdgcn_fence(__ATOMIC_ACQUIRE, "agent");
    if (tid < 128) {
      int o2 = tid >> 6;
      int lane2 = tid & 63;
      float acc2 = 0.f;
#pragma unroll
      for (int j = 0; j < 16; ++j)
        acc2 = fmaf(w2[o2 * 1024 + lane2 + j * 64], h[lane2 + j * 64], acc2);
#pragma unroll
      for (int off = 32; off >= 1; off >>= 1) acc2 += __shfl_down(acc2, off, 64);
      if (lane2 == 0) out[o2] = acc2 + b2[o2];
    }
  }
}

extern "C" void kernel_launch(void* const* d_in, const int* in_sizes, int n_in,
                              void* d_out, int out_size, void* d_ws, size_t ws_size,
                              hipStream_t stream) {
  const int*   words       = (const int*)d_in[0];
  const int*   wic         = (const int*)d_in[1];
  const float* word_emb    = (const float*)d_in[2];
  const float* chr_emb     = (const float*)d_in[3];
  const float* conv_chr_w  = (const float*)d_in[4];
  const float* conv_chr_b  = (const float*)d_in[5];
  const float* conv_sent_w = (const float*)d_in[6];
  const float* conv_sent_b = (const float*)d_in[7];
  const float* w1          = (const float*)d_in[8];
  const float* b1          = (const float*)d_in[9];
  const float* w2          = (const float*)d_in[10];
  const float* b2          = (const float*)d_in[11];
  float* out = (float*)d_out;

  float* ws    = (float*)d_ws;
  float* wT    = ws;                        // 196608 f
  float* part  = wT + 196608;               // 32768 f
  float* h_buf = part + 32768;              // 1024 f
  int*   ctr   = (int*)(h_buf + 1024);      // 4 ints
  short* Tb    = (short*)(ctr + 4);         // 98304 bf16
  short* u_base = Tb + 98304;               // 4098*512 bf16
  __hip_bfloat16* u0 = (__hip_bfloat16*)(u_base + 512);
  __hip_bfloat16* Wb = (__hip_bfloat16*)(u_base + 4098 * 512);

  prep_kernel<<<3841, 256, 0, stream>>>(conv_sent_w, conv_chr_w, wT, Wb,
                                        u_base, ctr);
  table_kernel<<<96, 256, 0, stream>>>(chr_emb, wT, (__hip_bfloat16*)Tb);
  char_word_kernel<<<512, 256, 0, stream>>>(words, wic, (const __hip_bfloat16*)Tb,
                                            word_emb, conv_chr_b, u0);
  sent_conv_mfma<<<dim3(64, 8), 256, 0, stream>>>(u0, Wb, part);
  fc12_kernel<<<128, 512, 0, stream>>>(part, conv_sent_b, w1, b1, w2, b2,
                                       h_buf, ctr, out);
}